// Round 5
// baseline (315.271 us; speedup 1.0000x reference)
//
#include <hip/hip_runtime.h>
#include <hip/hip_bf16.h>

typedef __bf16 v8bf __attribute__((ext_vector_type(8)));
typedef __bf16 v4bf __attribute__((ext_vector_type(4)));
typedef float  f32x4 __attribute__((ext_vector_type(4)));
typedef unsigned int u32;

#define NTOK 1024
#define HDIM 1024
#define FDIM 3584
#define NEXP 8
#define NPAIR 2048
#define MAXT1 32
#define MAXT2 32

// workspace layout (bytes)
#define OFF_COUNTS   0
#define OFF_OFFSETS  64
#define OFF_NT1      128
#define OFF_NT2      132
#define OFF_T1E      192
#define OFF_T1M      448
#define OFF_T2E      704
#define OFF_T2M      960
#define OFF_TOKIDX   2048
#define OFF_TOKWT    (2048 + 4*NPAIR)
#define OFF_PAIRTOK  (OFF_TOKWT + 4*NPAIR)
#define OFF_PAIRWT   (OFF_PAIRTOK + 4*NPAIR)
#define OFF_SLOTOF   (OFF_PAIRWT + 4*NPAIR)
#define OFF_XB       65536                          // bf16 [1024][1024] = 2 MB
#define OFF_ACT      (OFF_XB + 2ull*NTOK*HDIM)      // bf16 [2048][3584]
#define OFF_Y        (OFF_ACT + 2ull*NPAIR*FDIM)    // f32  [2048][1024]

static __device__ inline v4bf cvt4(float4 f) {
    v4bf r;
    r[0] = (__bf16)f.x; r[1] = (__bf16)f.y; r[2] = (__bf16)f.z; r[3] = (__bf16)f.w;
    return r;
}

// barrier with lgkm drain before and a compiler fence after (no vmcnt drain!)
#define BAR() do { asm volatile("s_waitcnt lgkmcnt(0)" ::: "memory"); \
                   __builtin_amdgcn_s_barrier(); \
                   asm volatile("" ::: "memory"); } while (0)

#define VMCNT0() asm volatile("s_waitcnt vmcnt(0)" ::: "memory")

// async 16B global -> LDS (linear dest: wave base + lane*16)
#define DMA16(SRC, DST) \
    __builtin_amdgcn_global_load_lds((const __attribute__((address_space(1))) u32*)(SRC), \
                                     (__attribute__((address_space(3))) u32*)(DST), 16, 0, 0)

// ---------------- x -> bf16 ----------------
__global__ __launch_bounds__(256) void moe_cvtx(const float* __restrict__ x,
                                                __bf16* __restrict__ xb)
{
    const size_t i = ((size_t)blockIdx.x * 256 + threadIdx.x) * 4;
    float4 v = *(const float4*)(x + i);
    *(v4bf*)(xb + i) = cvt4(v);
}

// ---------------- router ----------------
__global__ __launch_bounds__(256) void moe_router(
    const float* __restrict__ x, const float* __restrict__ gw,
    float* __restrict__ logits, int* __restrict__ counts,
    int* __restrict__ tok_idx, float* __restrict__ tok_wt)
{
    const int lane = threadIdx.x & 63;
    const int wv = threadIdx.x >> 6;
    const int t = blockIdx.x * 4 + wv;
    const float* xr = x + (size_t)t * HDIM;

    float acc[NEXP];
#pragma unroll
    for (int e = 0; e < NEXP; ++e) acc[e] = 0.f;
#pragma unroll
    for (int j = 0; j < 4; ++j) {
        int h = lane * 4 + j * 256;
        float4 xv = *(const float4*)(xr + h);
#pragma unroll
        for (int e = 0; e < NEXP; ++e) {
            float4 g = *(const float4*)(gw + e * HDIM + h);
            acc[e] += xv.x * g.x + xv.y * g.y + xv.z * g.z + xv.w * g.w;
        }
    }
#pragma unroll
    for (int e = 0; e < NEXP; ++e) {
#pragma unroll
        for (int s = 32; s > 0; s >>= 1) acc[e] += __shfl_xor(acc[e], s);
    }
    if (lane == 0) {
#pragma unroll
        for (int e = 0; e < NEXP; ++e) logits[t * NEXP + e] = acc[e];
        int i0 = 0;
#pragma unroll
        for (int e = 1; e < NEXP; ++e) if (acc[e] > acc[i0]) i0 = e;
        int i1 = (i0 == 0) ? 1 : 0;
#pragma unroll
        for (int e = 0; e < NEXP; ++e) if (e != i0 && acc[e] > acc[i1]) i1 = e;
        float w0 = 1.f / (1.f + expf(acc[i1] - acc[i0]));
        float w1 = 1.f - w0;
        tok_idx[2 * t] = i0; tok_idx[2 * t + 1] = i1;
        tok_wt[2 * t] = w0;  tok_wt[2 * t + 1] = w1;
        atomicAdd(&counts[i0], 1);
        atomicAdd(&counts[i1], 1);
    }
}

// ---------------- scatter + tile lists (BM=128 for both GEMMs) ----------------
__global__ void moe_scatter(const int* __restrict__ counts, const int* __restrict__ tok_idx,
                            const float* __restrict__ tok_wt, int* __restrict__ offsets,
                            int* __restrict__ pair_token, float* __restrict__ pair_wt,
                            int* __restrict__ slot_of,
                            int* __restrict__ t1e, int* __restrict__ t1m, int* __restrict__ nt1,
                            int* __restrict__ t2e, int* __restrict__ t2m, int* __restrict__ nt2)
{
    __shared__ int cur[NEXP];
    const int tid = threadIdx.x;
    if (tid == 0) {
        int run = 0, n1 = 0, n2 = 0;
        for (int e = 0; e < NEXP; ++e) {
            offsets[e] = run; cur[e] = run;
            for (int m0 = 0; m0 < counts[e]; m0 += 128) { t1e[n1] = e; t1m[n1] = m0; ++n1; }
            for (int m0 = 0; m0 < counts[e]; m0 += 128) { t2e[n2] = e; t2m[n2] = m0; ++n2; }
            run += counts[e];
        }
        *nt1 = n1; *nt2 = n2;
    }
    __syncthreads();
    for (int p = tid; p < 2 * NTOK; p += blockDim.x) {
        int e = tok_idx[p];
        int s = atomicAdd(&cur[e], 1);
        pair_token[s] = p >> 1;
        pair_wt[s] = tok_wt[p];
        slot_of[p] = s;
    }
}

// ---------------- GEMM1: act = silu(X@w1^T)*(X@w3^T); BM=128 BN=64 BK=32 ----------------
// A (bf16) staged via global_load_lds; B1/B3 (fp32) reg-staged + cvt.
// Per K-step: {stage-issue(next) -> CMP(cur) -> vmcnt(0) -> ST_B(next) -> barrier}
__global__ __launch_bounds__(256, 3) void moe_gemm1(
    const __bf16* __restrict__ xb, const float* __restrict__ w1g,
    const float* __restrict__ w3g, const int* __restrict__ counts,
    const int* __restrict__ offsets, const int* __restrict__ pair_token,
    const int* __restrict__ t1e, const int* __restrict__ t1m,
    const int* __restrict__ nt1,
    __bf16* __restrict__ act)
{
    const int ty = blockIdx.y;
    if (ty >= *nt1) return;
    const int e = t1e[ty];
    const int m0 = t1m[ty];
    const int Me = counts[e];
    const int rows = min(128, Me - m0);
    const int slot0 = offsets[e] + m0;
    const int n0 = blockIdx.x * 64;

    __shared__ __align__(16) __bf16 As[2][128 * 32];
    __shared__ __align__(16) __bf16 B1s[2][64 * 32];
    __shared__ __align__(16) __bf16 B3s[2][64 * 32];

    const int tid = threadIdx.x;
    const int lane = tid & 63;
    const int wv = tid >> 6;
    const int wm = (wv >> 1) * 64;
    const int wn = (wv & 1) * 32;
    const int lr = lane & 15;
    const int lk = (lane >> 4) * 8;

    f32x4 acc1[4][2], acc3[4][2];
#pragma unroll
    for (int i = 0; i < 4; ++i)
#pragma unroll
        for (int j = 0; j < 2; ++j) {
            acc1[i][j] = (f32x4){0.f, 0.f, 0.f, 0.f};
            acc3[i][j] = (f32x4){0.f, 0.f, 0.f, 0.f};
        }

    // A dma: 128x32 bf16 = 512 x 16B chunks; 2 per thread, lane-ordered within wave
    const __bf16* asrc[2];
    int adofs[2];
#pragma unroll
    for (int i = 0; i < 2; ++i) {
        int chunk = (i * 4 + wv) * 64 + lane;   // lane0 of wave = group base
        int row = chunk >> 2;
        int rr = (row < rows) ? row : 0;
        asrc[i] = xb + (size_t)pair_token[slot0 + rr] * HDIM + (chunk & 3) * 8;
        adofs[i] = chunk * 8;                   // element offset = chunk*16 bytes
    }
    // B: 64x32 f32 per matrix = 512 float4; 2 per thread
    const float* bsrc[2];
    int bdofs[2];
#pragma unroll
    for (int i = 0; i < 2; ++i) {
        int slot = tid + i * 256;
        int r = slot >> 3;
        int c = (slot & 7) * 4;
        bsrc[i]  = w1g + ((size_t)e * FDIM + n0 + r) * HDIM + c;
        bdofs[i] = r * 32 + c;
    }
    const ptrdiff_t d31 = w3g - w1g;

    int aoff[4], boff[2];
#pragma unroll
    for (int i = 0; i < 4; ++i) aoff[i] = (wm + i * 16 + lr) * 32 + lk;
#pragma unroll
    for (int i = 0; i < 2; ++i) boff[i] = (wn + i * 16 + lr) * 32 + lk;

    float4 b1v[2], b3v[2];

#define DMA_A1(BUF, K0) do { _Pragma("unroll") \
    for (int i = 0; i < 2; ++i) DMA16(asrc[i] + (K0), &As[BUF][adofs[i]]); } while (0)

#define LD_B1(K0) do { _Pragma("unroll") \
    for (int i = 0; i < 2; ++i) { b1v[i] = *(const float4*)(bsrc[i] + (K0)); \
                                  b3v[i] = *(const float4*)(bsrc[i] + d31 + (K0)); } } while (0)

#define ST_B1(BUF) do { _Pragma("unroll") \
    for (int i = 0; i < 2; ++i) { *(v4bf*)&B1s[BUF][bdofs[i]] = cvt4(b1v[i]); \
                                  *(v4bf*)&B3s[BUF][bdofs[i]] = cvt4(b3v[i]); } } while (0)

#define CMP1(BUF) do { v8bf af[4], b1f[2], b3f[2]; _Pragma("unroll") \
    for (int i = 0; i < 4; ++i) af[i] = *(const v8bf*)&As[BUF][aoff[i]]; \
    _Pragma("unroll") \
    for (int i = 0; i < 2; ++i) { b1f[i] = *(const v8bf*)&B1s[BUF][boff[i]]; \
                                  b3f[i] = *(const v8bf*)&B3s[BUF][boff[i]]; } \
    _Pragma("unroll") \
    for (int mi = 0; mi < 4; ++mi) { _Pragma("unroll") \
        for (int ni = 0; ni < 2; ++ni) { \
            acc1[mi][ni] = __builtin_amdgcn_mfma_f32_16x16x32_bf16(af[mi], b1f[ni], acc1[mi][ni], 0, 0, 0); \
            acc3[mi][ni] = __builtin_amdgcn_mfma_f32_16x16x32_bf16(af[mi], b3f[ni], acc3[mi][ni], 0, 0, 0); } } } while (0)

    // prologue: fill buffer 0
    DMA_A1(0, 0);
    LD_B1(0);
    VMCNT0();
    ST_B1(0);
    BAR();
    int buf = 0;
    for (int ks = 0; ks < HDIM / 32; ++ks) {
        const int kn = ks * 32 + 32;
        if (kn < HDIM) { DMA_A1(buf ^ 1, kn); LD_B1(kn); }   // issue next, fly during CMP
        CMP1(buf);
        if (kn < HDIM) { VMCNT0(); ST_B1(buf ^ 1); }         // drain after compute
        BAR();
        buf ^= 1;
    }
#undef DMA_A1
#undef LD_B1
#undef ST_B1
#undef CMP1

    const int rj = (lane >> 4) * 4;
#pragma unroll
    for (int mi = 0; mi < 4; ++mi) {
#pragma unroll
        for (int j = 0; j < 4; ++j) {
            int rm = wm + mi * 16 + rj + j;
            if (rm < rows) {
                size_t rowoff = (size_t)(slot0 + rm) * FDIM + n0 + wn;
#pragma unroll
                for (int ni = 0; ni < 2; ++ni) {
                    float h1 = acc1[mi][ni][j];
                    float h3 = acc3[mi][ni][j];
                    float sv = (h1 / (1.f + __expf(-h1))) * h3;
                    act[rowoff + ni * 16 + lr] = (__bf16)sv;
                }
            }
        }
    }
}

// ---------------- GEMM2: y = act @ w2^T; BM=128 BN=64 BK=32, K=3584 ----------------
__global__ __launch_bounds__(256, 4) void moe_gemm2(
    const __bf16* __restrict__ act, const float* __restrict__ w2g,
    const int* __restrict__ counts, const int* __restrict__ offsets,
    const int* __restrict__ t2e, const int* __restrict__ t2m,
    const int* __restrict__ nt2,
    float* __restrict__ y)
{
    const int ty = blockIdx.y;
    if (ty >= *nt2) return;
    const int e = t2e[ty];
    const int m0 = t2m[ty];
    const int Me = counts[e];
    const int rows = min(128, Me - m0);
    const int slot0 = offsets[e] + m0;
    const int n0 = blockIdx.x * 64;

    __shared__ __align__(16) __bf16 As[2][128 * 32];
    __shared__ __align__(16) __bf16 Bs[2][64 * 32];

    const int tid = threadIdx.x;
    const int lane = tid & 63;
    const int wv = tid >> 6;
    const int wm = (wv >> 1) * 64;
    const int wn = (wv & 1) * 32;
    const int lr = lane & 15;
    const int lk = (lane >> 4) * 8;

    f32x4 acc[4][2];
#pragma unroll
    for (int i = 0; i < 4; ++i)
#pragma unroll
        for (int j = 0; j < 2; ++j) acc[i][j] = (f32x4){0.f, 0.f, 0.f, 0.f};

    const __bf16* asrc[2];
    int adofs[2];
#pragma unroll
    for (int i = 0; i < 2; ++i) {
        int chunk = (i * 4 + wv) * 64 + lane;
        int row = chunk >> 2;
        int rr = (row < rows) ? row : 0;
        asrc[i] = act + (size_t)(slot0 + rr) * FDIM + (chunk & 3) * 8;
        adofs[i] = chunk * 8;
    }
    const float* bsrc[2];
    int bdofs[2];
#pragma unroll
    for (int i = 0; i < 2; ++i) {
        int slot = tid + i * 256;
        int r = slot >> 3;
        int c = (slot & 7) * 4;
        bsrc[i]  = w2g + ((size_t)e * HDIM + n0 + r) * FDIM + c;
        bdofs[i] = r * 32 + c;
    }

    int aoff[4], boff[2];
#pragma unroll
    for (int i = 0; i < 4; ++i) aoff[i] = (wm + i * 16 + lr) * 32 + lk;
#pragma unroll
    for (int i = 0; i < 2; ++i) boff[i] = (wn + i * 16 + lr) * 32 + lk;

    float4 bv[2];

#define DMA_A2(BUF, K0) do { _Pragma("unroll") \
    for (int i = 0; i < 2; ++i) DMA16(asrc[i] + (K0), &As[BUF][adofs[i]]); } while (0)

#define LD_B2(K0) do { _Pragma("unroll") \
    for (int i = 0; i < 2; ++i) bv[i] = *(const float4*)(bsrc[i] + (K0)); } while (0)

#define ST_B2(BUF) do { _Pragma("unroll") \
    for (int i = 0; i < 2; ++i) *(v4bf*)&Bs[BUF][bdofs[i]] = cvt4(bv[i]); } while (0)

#define CMP2(BUF) do { v8bf af[4], bf[2]; _Pragma("unroll") \
    for (int i = 0; i < 4; ++i) af[i] = *(const v8bf*)&As[BUF][aoff[i]]; \
    _Pragma("unroll") \
    for (int i = 0; i < 2; ++i) bf[i] = *(const v8bf*)&Bs[BUF][boff[i]]; \
    _Pragma("unroll") \
    for (int mi = 0; mi < 4; ++mi) { _Pragma("unroll") \
        for (int ni = 0; ni < 2; ++ni) \
            acc[mi][ni] = __builtin_amdgcn_mfma_f32_16x16x32_bf16(af[mi], bf[ni], acc[mi][ni], 0, 0, 0); } } while (0)

    DMA_A2(0, 0);
    LD_B2(0);
    VMCNT0();
    ST_B2(0);
    BAR();
    int buf = 0;
    for (int ks = 0; ks < FDIM / 32; ++ks) {
        const int kn = ks * 32 + 32;
        if (kn < FDIM) { DMA_A2(buf ^ 1, kn); LD_B2(kn); }
        CMP2(buf);
        if (kn < FDIM) { VMCNT0(); ST_B2(buf ^ 1); }
        BAR();
        buf ^= 1;
    }
#undef DMA_A2
#undef LD_B2
#undef ST_B2
#undef CMP2

    const int rj = (lane >> 4) * 4;
#pragma unroll
    for (int mi = 0; mi < 4; ++mi) {
#pragma unroll
        for (int j = 0; j < 4; ++j) {
            int rm = wm + mi * 16 + rj + j;
            if (rm < rows) {
                size_t rowoff = (size_t)(slot0 + rm) * HDIM + n0 + wn;
#pragma unroll
                for (int ni = 0; ni < 2; ++ni)
                    y[rowoff + ni * 16 + lr] = acc[mi][ni][j];
            }
        }
    }
}

// ---------------- combine ----------------
__global__ __launch_bounds__(256) void moe_combine(
    const float* __restrict__ y, const int* __restrict__ slot_of,
    const float* __restrict__ pair_wt, float* __restrict__ out)
{
    const int t = blockIdx.x;
    const int tid = threadIdx.x;
    const int s0 = slot_of[2 * t];
    const int s1 = slot_of[2 * t + 1];
    const float w0 = pair_wt[s0];
    const float w1 = pair_wt[s1];
    const float4 a = *(const float4*)(y + (size_t)s0 * HDIM + tid * 4);
    const float4 b = *(const float4*)(y + (size_t)s1 * HDIM + tid * 4);
    float4 o;
    o.x = w0 * a.x + w1 * b.x;
    o.y = w0 * a.y + w1 * b.y;
    o.z = w0 * a.z + w1 * b.z;
    o.w = w0 * a.w + w1 * b.w;
    *(float4*)(out + (size_t)t * HDIM + tid * 4) = o;
}

extern "C" void kernel_launch(void* const* d_in, const int* in_sizes, int n_in,
                              void* d_out, int out_size, void* d_ws, size_t ws_size,
                              hipStream_t stream) {
    const float* x   = (const float*)d_in[0];
    const float* gw  = (const float*)d_in[1];
    const float* w1  = (const float*)d_in[2];
    const float* w2  = (const float*)d_in[3];
    const float* w3  = (const float*)d_in[4];

    float* out    = (float*)d_out;
    float* logits = out + (size_t)NTOK * HDIM;

    char* ws = (char*)d_ws;
    int*    counts     = (int*)(ws + OFF_COUNTS);
    int*    offsets    = (int*)(ws + OFF_OFFSETS);
    int*    nt1        = (int*)(ws + OFF_NT1);
    int*    nt2        = (int*)(ws + OFF_NT2);
    int*    t1e        = (int*)(ws + OFF_T1E);
    int*    t1m        = (int*)(ws + OFF_T1M);
    int*    t2e        = (int*)(ws + OFF_T2E);
    int*    t2m        = (int*)(ws + OFF_T2M);
    int*    tok_idx    = (int*)(ws + OFF_TOKIDX);
    float*  tok_wt     = (float*)(ws + OFF_TOKWT);
    int*    pair_token = (int*)(ws + OFF_PAIRTOK);
    float*  pair_wt    = (float*)(ws + OFF_PAIRWT);
    int*    slot_of    = (int*)(ws + OFF_SLOTOF);
    __bf16* xb         = (__bf16*)(ws + OFF_XB);
    __bf16* act        = (__bf16*)(ws + OFF_ACT);
    float*  yb         = (float*)(ws + OFF_Y);

    hipMemsetAsync(counts, 0, 64, stream);

    moe_cvtx<<<dim3(NTOK * HDIM / 1024), dim3(256), 0, stream>>>(x, xb);
    moe_router<<<dim3(NTOK / 4), dim3(256), 0, stream>>>(x, gw, logits, counts, tok_idx, tok_wt);
    moe_scatter<<<dim3(1), dim3(256), 0, stream>>>(counts, tok_idx, tok_wt, offsets,
                                                   pair_token, pair_wt, slot_of,
                                                   t1e, t1m, nt1, t2e, t2m, nt2);
    moe_gemm1<<<dim3(FDIM / 64, MAXT1), dim3(256), 0, stream>>>(
        xb, w1, w3, counts, offsets, pair_token, t1e, t1m, nt1, act);
    moe_gemm2<<<dim3(HDIM / 64, MAXT2), dim3(256), 0, stream>>>(
        act, w2, counts, offsets, t2e, t2m, nt2, yb);
    moe_combine<<<dim3(NTOK), dim3(256), 0, stream>>>(yb, slot_of, pair_wt, out);
}

// Round 6
// 229.133 us; speedup vs baseline: 1.3759x; 1.3759x over previous
//
#include <hip/hip_runtime.h>
#include <hip/hip_bf16.h>

typedef __bf16 v8bf __attribute__((ext_vector_type(8)));
typedef __bf16 v4bf __attribute__((ext_vector_type(4)));
typedef float  f32x4 __attribute__((ext_vector_type(4)));
typedef unsigned int u32;

#define NTOK 1024
#define HDIM 1024
#define FDIM 3584
#define NEXP 8
#define NPAIR 2048
#define MAXT1 32   // BM=128 tiles
#define MAXT2 48   // BM=64 tiles

// workspace layout (bytes)
#define OFF_COUNTS   0
#define OFF_OFFSETS  64
#define OFF_NT1      128
#define OFF_NT2      132
#define OFF_T1E      192
#define OFF_T1M      320
#define OFF_T2E      448
#define OFF_T2M      640
#define OFF_TOKIDX   2048
#define OFF_TOKWT    (2048 + 4*NPAIR)
#define OFF_PAIRTOK  (OFF_TOKWT + 4*NPAIR)
#define OFF_PAIRWT   (OFF_PAIRTOK + 4*NPAIR)
#define OFF_SLOTOF   (OFF_PAIRWT + 4*NPAIR)
#define OFF_XB       65536                          // bf16 [1024][1024] = 2 MB
#define OFF_ACT      (OFF_XB + 2ull*NTOK*HDIM)      // bf16 [2048][3584]
#define OFF_Y        (OFF_ACT + 2ull*NPAIR*FDIM)    // f32  [2048][1024]

static __device__ inline v4bf cvt4(float4 f) {
    v4bf r;
    r[0] = (__bf16)f.x; r[1] = (__bf16)f.y; r[2] = (__bf16)f.z; r[3] = (__bf16)f.w;
    return r;
}

static __device__ inline v8bf pack8(f32x4 lo, f32x4 hi) {
    v8bf r;
    r[0] = (__bf16)lo[0]; r[1] = (__bf16)lo[1]; r[2] = (__bf16)lo[2]; r[3] = (__bf16)lo[3];
    r[4] = (__bf16)hi[0]; r[5] = (__bf16)hi[1]; r[6] = (__bf16)hi[2]; r[7] = (__bf16)hi[3];
    return r;
}

#define FENCE() asm volatile("" ::: "memory")
#define BARRIER() do { FENCE(); __builtin_amdgcn_s_barrier(); FENCE(); } while (0)
#define WAITVM(N) asm volatile("s_waitcnt vmcnt(" #N ")" ::: "memory")

// async 16B global->LDS; DST must be the wave-uniform base (HW adds lane*16)
#define DMA16(SRC, DST) \
    __builtin_amdgcn_global_load_lds((const __attribute__((address_space(1))) u32*)(SRC), \
                                     (__attribute__((address_space(3))) u32*)(DST), 16, 0, 0)

// ---------------- x -> bf16 ----------------
__global__ __launch_bounds__(256) void moe_cvtx(const float* __restrict__ x,
                                                __bf16* __restrict__ xb)
{
    const size_t i = ((size_t)blockIdx.x * 256 + threadIdx.x) * 4;
    float4 v = *(const float4*)(x + i);
    *(v4bf*)(xb + i) = cvt4(v);
}

// ---------------- router ----------------
__global__ __launch_bounds__(256) void moe_router(
    const float* __restrict__ x, const float* __restrict__ gw,
    float* __restrict__ logits, int* __restrict__ counts,
    int* __restrict__ tok_idx, float* __restrict__ tok_wt)
{
    const int lane = threadIdx.x & 63;
    const int wv = threadIdx.x >> 6;
    const int t = blockIdx.x * 4 + wv;
    const float* xr = x + (size_t)t * HDIM;

    float acc[NEXP];
#pragma unroll
    for (int e = 0; e < NEXP; ++e) acc[e] = 0.f;
#pragma unroll
    for (int j = 0; j < 4; ++j) {
        int h = lane * 4 + j * 256;
        float4 xv = *(const float4*)(xr + h);
#pragma unroll
        for (int e = 0; e < NEXP; ++e) {
            float4 g = *(const float4*)(gw + e * HDIM + h);
            acc[e] += xv.x * g.x + xv.y * g.y + xv.z * g.z + xv.w * g.w;
        }
    }
#pragma unroll
    for (int e = 0; e < NEXP; ++e) {
#pragma unroll
        for (int s = 32; s > 0; s >>= 1) acc[e] += __shfl_xor(acc[e], s);
    }
    if (lane == 0) {
#pragma unroll
        for (int e = 0; e < NEXP; ++e) logits[t * NEXP + e] = acc[e];
        int i0 = 0;
#pragma unroll
        for (int e = 1; e < NEXP; ++e) if (acc[e] > acc[i0]) i0 = e;
        int i1 = (i0 == 0) ? 1 : 0;
#pragma unroll
        for (int e = 0; e < NEXP; ++e) if (e != i0 && acc[e] > acc[i1]) i1 = e;
        float w0 = 1.f / (1.f + expf(acc[i1] - acc[i0]));
        float w1 = 1.f - w0;
        tok_idx[2 * t] = i0; tok_idx[2 * t + 1] = i1;
        tok_wt[2 * t] = w0;  tok_wt[2 * t + 1] = w1;
        atomicAdd(&counts[i0], 1);
        atomicAdd(&counts[i1], 1);
    }
}

// ---------------- scatter + tile lists ----------------
__global__ void moe_scatter(const int* __restrict__ counts, const int* __restrict__ tok_idx,
                            const float* __restrict__ tok_wt, int* __restrict__ offsets,
                            int* __restrict__ pair_token, float* __restrict__ pair_wt,
                            int* __restrict__ slot_of,
                            int* __restrict__ t1e, int* __restrict__ t1m, int* __restrict__ nt1,
                            int* __restrict__ t2e, int* __restrict__ t2m, int* __restrict__ nt2)
{
    __shared__ int cur[NEXP];
    const int tid = threadIdx.x;
    if (tid == 0) {
        int run = 0, n1 = 0, n2 = 0;
        for (int e = 0; e < NEXP; ++e) {
            offsets[e] = run; cur[e] = run;
            for (int m0 = 0; m0 < counts[e]; m0 += 128) { t1e[n1] = e; t1m[n1] = m0; ++n1; }
            for (int m0 = 0; m0 < counts[e]; m0 += 64)  { t2e[n2] = e; t2m[n2] = m0; ++n2; }
            run += counts[e];
        }
        *nt1 = n1; *nt2 = n2;
    }
    __syncthreads();
    for (int p = tid; p < 2 * NTOK; p += blockDim.x) {
        int e = tok_idx[p];
        int s = atomicAdd(&cur[e], 1);
        pair_token[s] = p >> 1;
        pair_wt[s] = tok_wt[p];
        slot_of[p] = s;
    }
}

// ---------------- GEMM1: act = silu(X@w1^T)*(X@w3^T); BM=128 BN=64 BK=32 ----------------
// All staging via global_load_lds (A bf16, B fp32). Counted vmcnt(6).
// LDS read swizzle: A byte ^((row&3)<<4), B byte ^((row&7)<<4); sources pre-swizzled.
__global__ __launch_bounds__(256, 2) void moe_gemm1(
    const __bf16* __restrict__ xb, const float* __restrict__ w1g,
    const float* __restrict__ w3g, const int* __restrict__ counts,
    const int* __restrict__ offsets, const int* __restrict__ pair_token,
    const int* __restrict__ t1e, const int* __restrict__ t1m,
    const int* __restrict__ nt1,
    __bf16* __restrict__ act)
{
    const int ty = blockIdx.y;
    if (ty >= *nt1) return;
    const int e = t1e[ty];
    const int m0 = t1m[ty];
    const int Me = counts[e];
    const int rows = min(128, Me - m0);
    const int slot0 = offsets[e] + m0;
    const int n0 = blockIdx.x * 64;

    __shared__ __align__(16) __bf16 As[2][128 * 32];   // 8 KB per buf
    __shared__ __align__(16) float  B1s[2][64 * 32];   // 8 KB per buf
    __shared__ __align__(16) float  B3s[2][64 * 32];

    const int tid = threadIdx.x;
    const int lane = tid & 63;
    const int wv = tid >> 6;
    const int wm = (wv >> 1) * 64;
    const int wn = (wv & 1) * 32;
    const int lr = lane & 15;
    const int lk = (lane >> 4) * 8;

    f32x4 acc1[4][2], acc3[4][2];
#pragma unroll
    for (int i = 0; i < 4; ++i)
#pragma unroll
        for (int j = 0; j < 2; ++j) {
            acc1[i][j] = (f32x4){0.f, 0.f, 0.f, 0.f};
            acc3[i][j] = (f32x4){0.f, 0.f, 0.f, 0.f};
        }

    // ---- DMA source setup (per-lane src, wave-uniform dest base) ----
    // A: 512 chunks of 16B; chunk c = i*256 + tid; row = c>>2, colblk j = c&3
    const char* asrc[2];
#pragma unroll
    for (int i = 0; i < 2; ++i) {
        int c = i * 256 + tid;
        int r = c >> 2;
        int rr = (r < rows) ? r : 0;
        int sj = (c & 3) ^ (r & 3);                 // pre-swizzled source col block
        asrc[i] = (const char*)(xb + (size_t)pair_token[slot0 + rr] * HDIM + sj * 8);
    }
    const int adst_base0 = (0 * 256 + wv * 64) * 16;   // byte offset of wave's region
    const int adst_base1 = (1 * 256 + wv * 64) * 16;

    // B: 512 chunks of 16B per matrix; row = c>>3, colblk j = c&7
    const char* b1src[2];
#pragma unroll
    for (int i = 0; i < 2; ++i) {
        int c = i * 256 + tid;
        int r = c >> 3;
        int sj = (c & 7) ^ (r & 7);
        b1src[i] = (const char*)(w1g + ((size_t)e * FDIM + n0 + r) * HDIM + sj * 4);
    }
    const ptrdiff_t d31b = (const char*)w3g - (const char*)w1g;
    const int bdst_base0 = (0 * 256 + wv * 64) * 16;
    const int bdst_base1 = (1 * 256 + wv * 64) * 16;

    // ---- swizzled read offsets (bytes) ----
    int aoff[4], boff[2];
#pragma unroll
    for (int i = 0; i < 4; ++i) {
        int row = wm + i * 16 + lr;
        aoff[i] = (row * 64 + lk * 2) ^ ((row & 3) << 4);
    }
#pragma unroll
    for (int i = 0; i < 2; ++i) {
        int row = wn + i * 16 + lr;
        boff[i] = (row * 128 + lk * 4) ^ ((row & 7) << 4);
    }

#define DMA_ALL1(BUF, K0) do { \
    DMA16(asrc[0] + (size_t)(K0) * 2, (char*)&As[BUF][0] + adst_base0); \
    DMA16(asrc[1] + (size_t)(K0) * 2, (char*)&As[BUF][0] + adst_base1); \
    DMA16(b1src[0] + (size_t)(K0) * 4, (char*)&B1s[BUF][0] + bdst_base0); \
    DMA16(b1src[1] + (size_t)(K0) * 4, (char*)&B1s[BUF][0] + bdst_base1); \
    DMA16(b1src[0] + d31b + (size_t)(K0) * 4, (char*)&B3s[BUF][0] + bdst_base0); \
    DMA16(b1src[1] + d31b + (size_t)(K0) * 4, (char*)&B3s[BUF][0] + bdst_base1); \
} while (0)

#define CMP1(BUF) do { \
    v8bf af[4], b1f[2], b3f[2]; \
    _Pragma("unroll") \
    for (int i = 0; i < 4; ++i) af[i] = *(const v8bf*)((const char*)&As[BUF][0] + aoff[i]); \
    _Pragma("unroll") \
    for (int i = 0; i < 2; ++i) { \
        f32x4 lo1 = *(const f32x4*)((const char*)&B1s[BUF][0] + boff[i]); \
        f32x4 hi1 = *(const f32x4*)((const char*)&B1s[BUF][0] + (boff[i] ^ 16)); \
        f32x4 lo3 = *(const f32x4*)((const char*)&B3s[BUF][0] + boff[i]); \
        f32x4 hi3 = *(const f32x4*)((const char*)&B3s[BUF][0] + (boff[i] ^ 16)); \
        b1f[i] = pack8(lo1, hi1); \
        b3f[i] = pack8(lo3, hi3); \
    } \
    _Pragma("unroll") \
    for (int mi = 0; mi < 4; ++mi) { \
        _Pragma("unroll") \
        for (int ni = 0; ni < 2; ++ni) { \
            acc1[mi][ni] = __builtin_amdgcn_mfma_f32_16x16x32_bf16(af[mi], b1f[ni], acc1[mi][ni], 0, 0, 0); \
            acc3[mi][ni] = __builtin_amdgcn_mfma_f32_16x16x32_bf16(af[mi], b3f[ni], acc3[mi][ni], 0, 0, 0); \
        } } } while (0)

    DMA_ALL1(0, 0);
    int buf = 0;
    for (int ks = 0; ks < HDIM / 32; ++ks) {
        if (ks + 1 < HDIM / 32) {
            DMA_ALL1(buf ^ 1, (ks + 1) * 32);
            WAITVM(6);                      // previous tile's 6 DMAs landed; fresh 6 in flight
        } else {
            WAITVM(0);
        }
        BARRIER();
        CMP1(buf);
        BARRIER();                          // all waves done reading before next overwrite
        buf ^= 1;
    }
#undef DMA_ALL1
#undef CMP1

    const int rj = (lane >> 4) * 4;
#pragma unroll
    for (int mi = 0; mi < 4; ++mi) {
#pragma unroll
        for (int j = 0; j < 4; ++j) {
            int rm = wm + mi * 16 + rj + j;
            if (rm < rows) {
                size_t rowoff = (size_t)(slot0 + rm) * FDIM + n0 + wn;
#pragma unroll
                for (int ni = 0; ni < 2; ++ni) {
                    float h1 = acc1[mi][ni][j];
                    float h3 = acc3[mi][ni][j];
                    float sv = (h1 / (1.f + __expf(-h1))) * h3;
                    act[rowoff + ni * 16 + lr] = (__bf16)sv;
                }
            }
        }
    }
}

// ---------------- GEMM2: y = act @ w2^T; BM=64 BN=32 BK=32 ----------------
__global__ __launch_bounds__(256, 2) void moe_gemm2(
    const __bf16* __restrict__ act, const float* __restrict__ w2g,
    const int* __restrict__ counts, const int* __restrict__ offsets,
    const int* __restrict__ t2e, const int* __restrict__ t2m,
    const int* __restrict__ nt2,
    float* __restrict__ y)
{
    const int ty = blockIdx.y;
    if (ty >= *nt2) return;
    const int e = t2e[ty];
    const int m0 = t2m[ty];
    const int Me = counts[e];
    const int rows = min(64, Me - m0);
    const int slot0 = offsets[e] + m0;
    const int n0 = blockIdx.x * 32;

    __shared__ __align__(16) __bf16 As[2][64 * 32];   // 4 KB per buf
    __shared__ __align__(16) float  Bs[2][32 * 32];   // 4 KB per buf

    const int tid = threadIdx.x;
    const int lane = tid & 63;
    const int wv = tid >> 6;
    const int wm = (wv >> 1) * 32;   // 2m x 2n waves, wave tile 32x16
    const int wn = (wv & 1) * 16;
    const int lr = lane & 15;
    const int lk = (lane >> 4) * 8;

    f32x4 acc[2];
    acc[0] = (f32x4){0.f, 0.f, 0.f, 0.f};
    acc[1] = (f32x4){0.f, 0.f, 0.f, 0.f};

    // A: 256 chunks; c = tid; row = c>>2
    const char* asrc;
    {
        int c = tid;
        int r = c >> 2;
        int rr = (r < rows) ? r : 0;
        int sj = (c & 3) ^ (r & 3);
        asrc = (const char*)(act + (size_t)(slot0 + rr) * FDIM + sj * 8);
    }
    const int adst_base = (wv * 64) * 16;
    // B: 256 chunks; c = tid; row = c>>3 (0..31)
    const char* bsrc;
    {
        int c = tid;
        int r = c >> 3;
        int sj = (c & 7) ^ (r & 7);
        bsrc = (const char*)(w2g + ((size_t)e * HDIM + n0 + r) * FDIM + sj * 4);
    }
    const int bdst_base = (wv * 64) * 16;

    int aoff[2], boff;
#pragma unroll
    for (int i = 0; i < 2; ++i) {
        int row = wm + i * 16 + lr;
        aoff[i] = (row * 64 + lk * 2) ^ ((row & 3) << 4);
    }
    {
        int row = wn + lr;
        boff = (row * 128 + lk * 4) ^ ((row & 7) << 4);
    }

#define DMA_ALL2(BUF, K0) do { \
    DMA16(asrc + (size_t)(K0) * 2, (char*)&As[BUF][0] + adst_base); \
    DMA16(bsrc + (size_t)(K0) * 4, (char*)&Bs[BUF][0] + bdst_base); \
} while (0)

#define CMP2(BUF) do { \
    v8bf af[2], bf; \
    _Pragma("unroll") \
    for (int i = 0; i < 2; ++i) af[i] = *(const v8bf*)((const char*)&As[BUF][0] + aoff[i]); \
    { \
        f32x4 lo = *(const f32x4*)((const char*)&Bs[BUF][0] + boff); \
        f32x4 hi = *(const f32x4*)((const char*)&Bs[BUF][0] + (boff ^ 16)); \
        bf = pack8(lo, hi); \
    } \
    acc[0] = __builtin_amdgcn_mfma_f32_16x16x32_bf16(af[0], bf, acc[0], 0, 0, 0); \
    acc[1] = __builtin_amdgcn_mfma_f32_16x16x32_bf16(af[1], bf, acc[1], 0, 0, 0); \
} while (0)

    DMA_ALL2(0, 0);
    int buf = 0;
    for (int ks = 0; ks < FDIM / 32; ++ks) {
        if (ks + 1 < FDIM / 32) {
            DMA_ALL2(buf ^ 1, (ks + 1) * 32);
            WAITVM(2);
        } else {
            WAITVM(0);
        }
        BARRIER();
        CMP2(buf);
        BARRIER();
        buf ^= 1;
    }
#undef DMA_ALL2
#undef CMP2

    const int rj = (lane >> 4) * 4;
#pragma unroll
    for (int mi = 0; mi < 2; ++mi) {
#pragma unroll
        for (int j = 0; j < 4; ++j) {
            int rm = wm + mi * 16 + rj + j;
            if (rm < rows) {
                y[(size_t)(slot0 + rm) * HDIM + n0 + wn + lr] = acc[mi][j];
            }
        }
    }
}

// ---------------- combine ----------------
__global__ __launch_bounds__(256) void moe_combine(
    const float* __restrict__ y, const int* __restrict__ slot_of,
    const float* __restrict__ pair_wt, float* __restrict__ out)
{
    const int t = blockIdx.x;
    const int tid = threadIdx.x;
    const int s0 = slot_of[2 * t];
    const int s1 = slot_of[2 * t + 1];
    const float w0 = pair_wt[s0];
    const float w1 = pair_wt[s1];
    const float4 a = *(const float4*)(y + (size_t)s0 * HDIM + tid * 4);
    const float4 b = *(const float4*)(y + (size_t)s1 * HDIM + tid * 4);
    float4 o;
    o.x = w0 * a.x + w1 * b.x;
    o.y = w0 * a.y + w1 * b.y;
    o.z = w0 * a.z + w1 * b.z;
    o.w = w0 * a.w + w1 * b.w;
    *(float4*)(out + (size_t)t * HDIM + tid * 4) = o;
}

extern "C" void kernel_launch(void* const* d_in, const int* in_sizes, int n_in,
                              void* d_out, int out_size, void* d_ws, size_t ws_size,
                              hipStream_t stream) {
    const float* x   = (const float*)d_in[0];
    const float* gw  = (const float*)d_in[1];
    const float* w1  = (const float*)d_in[2];
    const float* w2  = (const float*)d_in[3];
    const float* w3  = (const float*)d_in[4];

    float* out    = (float*)d_out;
    float* logits = out + (size_t)NTOK * HDIM;

    char* ws = (char*)d_ws;
    int*    counts     = (int*)(ws + OFF_COUNTS);
    int*    offsets    = (int*)(ws + OFF_OFFSETS);
    int*    nt1        = (int*)(ws + OFF_NT1);
    int*    nt2        = (int*)(ws + OFF_NT2);
    int*    t1e        = (int*)(ws + OFF_T1E);
    int*    t1m        = (int*)(ws + OFF_T1M);
    int*    t2e        = (int*)(ws + OFF_T2E);
    int*    t2m        = (int*)(ws + OFF_T2M);
    int*    tok_idx    = (int*)(ws + OFF_TOKIDX);
    float*  tok_wt     = (float*)(ws + OFF_TOKWT);
    int*    pair_token = (int*)(ws + OFF_PAIRTOK);
    float*  pair_wt    = (float*)(ws + OFF_PAIRWT);
    int*    slot_of    = (int*)(ws + OFF_SLOTOF);
    __bf16* xb         = (__bf16*)(ws + OFF_XB);
    __bf16* act        = (__bf16*)(ws + OFF_ACT);
    float*  yb         = (float*)(ws + OFF_Y);

    hipMemsetAsync(counts, 0, 64, stream);

    moe_cvtx<<<dim3(NTOK * HDIM / 1024), dim3(256), 0, stream>>>(x, xb);
    moe_router<<<dim3(NTOK / 4), dim3(256), 0, stream>>>(x, gw, logits, counts, tok_idx, tok_wt);
    moe_scatter<<<dim3(1), dim3(256), 0, stream>>>(counts, tok_idx, tok_wt, offsets,
                                                   pair_token, pair_wt, slot_of,
                                                   t1e, t1m, nt1, t2e, t2m, nt2);
    moe_gemm1<<<dim3(FDIM / 64, MAXT1), dim3(256), 0, stream>>>(
        xb, w1, w3, counts, offsets, pair_token, t1e, t1m, nt1, act);
    moe_gemm2<<<dim3(HDIM / 32, MAXT2), dim3(256), 0, stream>>>(
        act, w2, counts, offsets, t2e, t2m, nt2, yb);
    moe_combine<<<dim3(NTOK), dim3(256), 0, stream>>>(yb, slot_of, pair_wt, out);
}

// Round 7
// 196.332 us; speedup vs baseline: 1.6058x; 1.1671x over previous
//
#include <hip/hip_runtime.h>
#include <hip/hip_bf16.h>

typedef __bf16 v8bf __attribute__((ext_vector_type(8)));
typedef __bf16 v4bf __attribute__((ext_vector_type(4)));
typedef float  f32x4 __attribute__((ext_vector_type(4)));
typedef unsigned int u32;

#define NTOK 1024
#define HDIM 1024
#define FDIM 3584
#define NEXP 8
#define NPAIR 2048
#define MAXT1 32   // BM=128 tiles
#define MAXT2 48   // BM=64 tiles
#define KSPLIT2 2
#define KPER2 (FDIM / KSPLIT2)

// workspace layout (bytes)
#define OFF_COUNTS   0
#define OFF_OFFSETS  64
#define OFF_NT1      128
#define OFF_NT2      132
#define OFF_T1E      192
#define OFF_T1M      320
#define OFF_T2E      448
#define OFF_T2M      640
#define OFF_TOKIDX   2048
#define OFF_TOKWT    (2048 + 4*NPAIR)
#define OFF_PAIRTOK  (OFF_TOKWT + 4*NPAIR)
#define OFF_PAIRWT   (OFF_PAIRTOK + 4*NPAIR)
#define OFF_SLOTOF   (OFF_PAIRWT + 4*NPAIR)
#define OFF_XB       65536                          // bf16 [1024][1024] = 2 MB
#define OFF_ACT      (OFF_XB + 2ull*NTOK*HDIM)      // bf16 [2048][3584]
#define OFF_Y0       (OFF_ACT + 2ull*NPAIR*FDIM)    // f32  [2048][1024]
#define OFF_Y1       (OFF_Y0 + 4ull*NPAIR*HDIM)     // f32  [2048][1024]

static __device__ inline v4bf cvt4(float4 f) {
    v4bf r;
    r[0] = (__bf16)f.x; r[1] = (__bf16)f.y; r[2] = (__bf16)f.z; r[3] = (__bf16)f.w;
    return r;
}

static __device__ inline v8bf pack8(f32x4 lo, f32x4 hi) {
    v8bf r;
    r[0] = (__bf16)lo[0]; r[1] = (__bf16)lo[1]; r[2] = (__bf16)lo[2]; r[3] = (__bf16)lo[3];
    r[4] = (__bf16)hi[0]; r[5] = (__bf16)hi[1]; r[6] = (__bf16)hi[2]; r[7] = (__bf16)hi[3];
    return r;
}

#define FENCE() asm volatile("" ::: "memory")
#define BARRIER() do { FENCE(); __builtin_amdgcn_s_barrier(); FENCE(); } while (0)
#define WAITVM0() asm volatile("s_waitcnt vmcnt(0)" ::: "memory")
#define WAITLGKM0() asm volatile("s_waitcnt lgkmcnt(0)" ::: "memory")

// async 16B global->LDS; DST is the wave-uniform base (HW adds lane*16)
#define DMA16(SRC, DST) \
    __builtin_amdgcn_global_load_lds((const __attribute__((address_space(1))) u32*)(SRC), \
                                     (__attribute__((address_space(3))) u32*)(DST), 16, 0, 0)

// ---------------- x -> bf16 ----------------
__global__ __launch_bounds__(256) void moe_cvtx(const float* __restrict__ x,
                                                __bf16* __restrict__ xb)
{
    const size_t i = ((size_t)blockIdx.x * 256 + threadIdx.x) * 4;
    float4 v = *(const float4*)(x + i);
    *(v4bf*)(xb + i) = cvt4(v);
}

// ---------------- router ----------------
__global__ __launch_bounds__(256) void moe_router(
    const float* __restrict__ x, const float* __restrict__ gw,
    float* __restrict__ logits, int* __restrict__ counts,
    int* __restrict__ tok_idx, float* __restrict__ tok_wt)
{
    const int lane = threadIdx.x & 63;
    const int wv = threadIdx.x >> 6;
    const int t = blockIdx.x * 4 + wv;
    const float* xr = x + (size_t)t * HDIM;

    float acc[NEXP];
#pragma unroll
    for (int e = 0; e < NEXP; ++e) acc[e] = 0.f;
#pragma unroll
    for (int j = 0; j < 4; ++j) {
        int h = lane * 4 + j * 256;
        float4 xv = *(const float4*)(xr + h);
#pragma unroll
        for (int e = 0; e < NEXP; ++e) {
            float4 g = *(const float4*)(gw + e * HDIM + h);
            acc[e] += xv.x * g.x + xv.y * g.y + xv.z * g.z + xv.w * g.w;
        }
    }
#pragma unroll
    for (int e = 0; e < NEXP; ++e) {
#pragma unroll
        for (int s = 32; s > 0; s >>= 1) acc[e] += __shfl_xor(acc[e], s);
    }
    if (lane == 0) {
#pragma unroll
        for (int e = 0; e < NEXP; ++e) logits[t * NEXP + e] = acc[e];
        int i0 = 0;
#pragma unroll
        for (int e = 1; e < NEXP; ++e) if (acc[e] > acc[i0]) i0 = e;
        int i1 = (i0 == 0) ? 1 : 0;
#pragma unroll
        for (int e = 0; e < NEXP; ++e) if (e != i0 && acc[e] > acc[i1]) i1 = e;
        float w0 = 1.f / (1.f + expf(acc[i1] - acc[i0]));
        float w1 = 1.f - w0;
        tok_idx[2 * t] = i0; tok_idx[2 * t + 1] = i1;
        tok_wt[2 * t] = w0;  tok_wt[2 * t + 1] = w1;
        atomicAdd(&counts[i0], 1);
        atomicAdd(&counts[i1], 1);
    }
}

// ---------------- scatter + tile lists ----------------
__global__ void moe_scatter(const int* __restrict__ counts, const int* __restrict__ tok_idx,
                            const float* __restrict__ tok_wt, int* __restrict__ offsets,
                            int* __restrict__ pair_token, float* __restrict__ pair_wt,
                            int* __restrict__ slot_of,
                            int* __restrict__ t1e, int* __restrict__ t1m, int* __restrict__ nt1,
                            int* __restrict__ t2e, int* __restrict__ t2m, int* __restrict__ nt2)
{
    __shared__ int cur[NEXP];
    const int tid = threadIdx.x;
    if (tid == 0) {
        int run = 0, n1 = 0, n2 = 0;
        for (int e = 0; e < NEXP; ++e) {
            offsets[e] = run; cur[e] = run;
            for (int m0 = 0; m0 < counts[e]; m0 += 128) { t1e[n1] = e; t1m[n1] = m0; ++n1; }
            for (int m0 = 0; m0 < counts[e]; m0 += 64)  { t2e[n2] = e; t2m[n2] = m0; ++n2; }
            run += counts[e];
        }
        *nt1 = n1; *nt2 = n2;
    }
    __syncthreads();
    for (int p = tid; p < 2 * NTOK; p += blockDim.x) {
        int e = tok_idx[p];
        int s = atomicAdd(&cur[e], 1);
        pair_token[s] = p >> 1;
        pair_wt[s] = tok_wt[p];
        slot_of[p] = s;
    }
}

// ---------------- GEMM1: act = silu(X@w1^T)*(X@w3^T); BM=128 BN=64 BK=64, single-buf ----------------
// m97 pattern: DMA -> vmcnt(0) -> bar -> MFMA -> lgkm(0) -> bar -> DMA(next).
// A bf16 (16KB), B1/B3 fp32 (16KB each) in LDS. Both-sides XOR swizzle.
__global__ __launch_bounds__(256, 2) void moe_gemm1(
    const __bf16* __restrict__ xb, const float* __restrict__ w1g,
    const float* __restrict__ w3g, const int* __restrict__ counts,
    const int* __restrict__ offsets, const int* __restrict__ pair_token,
    const int* __restrict__ t1e, const int* __restrict__ t1m,
    const int* __restrict__ nt1,
    __bf16* __restrict__ act)
{
    const int ty = blockIdx.y;
    if (ty >= *nt1) return;
    const int e = t1e[ty];
    const int m0 = t1m[ty];
    const int Me = counts[e];
    const int rows = min(128, Me - m0);
    const int slot0 = offsets[e] + m0;
    const int n0 = blockIdx.x * 64;

    __shared__ __align__(16) __bf16 As[128 * 64];    // 16 KB
    __shared__ __align__(16) float  B1s[64 * 64];    // 16 KB
    __shared__ __align__(16) float  B3s[64 * 64];    // 16 KB

    const int tid = threadIdx.x;
    const int lane = tid & 63;
    const int wv = tid >> 6;
    const int ln4 = lane >> 4;          // 0..3
    const int lr = lane & 15;
    const int wm = (wv >> 1) * 64;
    const int wn = (wv & 1) * 32;

    f32x4 acc1[4][2], acc3[4][2];
#pragma unroll
    for (int i = 0; i < 4; ++i)
#pragma unroll
        for (int j = 0; j < 2; ++j) {
            acc1[i][j] = (f32x4){0.f, 0.f, 0.f, 0.f};
            acc3[i][j] = (f32x4){0.f, 0.f, 0.f, 0.f};
        }

    // A: 1024 chunks of 16B (128 rows x 8 chunks); 4 per thread
    const char* asrc[4];
#pragma unroll
    for (int i = 0; i < 4; ++i) {
        int c = i * 256 + tid;
        int r = c >> 3;
        int rr = (r < rows) ? r : 0;
        int sj = (c & 7) ^ (r & 7);
        asrc[i] = (const char*)(xb + (size_t)pair_token[slot0 + rr] * HDIM) + sj * 16;
    }
    // B: 1024 chunks per matrix (64 rows x 16 chunks); 4 per thread per matrix
    const char* bsrc[4];
#pragma unroll
    for (int i = 0; i < 4; ++i) {
        int c = i * 256 + tid;
        int r = c >> 4;
        int sj = (c & 15) ^ (r & 15);
        bsrc[i] = (const char*)(w1g + ((size_t)e * FDIM + n0 + r) * HDIM) + sj * 16;
    }
    const ptrdiff_t d31b = (const char*)w3g - (const char*)w1g;

#define DMA_ALL1(K0) do { _Pragma("unroll") \
    for (int i = 0; i < 4; ++i) { \
        DMA16(asrc[i] + (size_t)(K0) * 128, (char*)As + (i * 256 + wv * 64) * 16); \
        DMA16(bsrc[i] + (size_t)(K0) * 256, (char*)B1s + (i * 256 + wv * 64) * 16); \
        DMA16(bsrc[i] + d31b + (size_t)(K0) * 256, (char*)B3s + (i * 256 + wv * 64) * 16); \
    } } while (0)

    // read offsets
    int abase[4], axor[4];
#pragma unroll
    for (int i = 0; i < 4; ++i) {
        int row = wm + i * 16 + lr;
        abase[i] = row * 128;
        axor[i] = (row & 7) << 4;
    }
    int bbase[2], bxor[2];
#pragma unroll
    for (int i = 0; i < 2; ++i) {
        int row = wn + i * 16 + lr;
        bbase[i] = row * 256;
        bxor[i] = (row & 15) << 4;
    }

#define CMP1() do { \
    v8bf af[4][2]; v8bf b1f[2][2], b3f[2][2]; \
    _Pragma("unroll") \
    for (int mi = 0; mi < 4; ++mi) { _Pragma("unroll") \
        for (int ks = 0; ks < 2; ++ks) \
            af[mi][ks] = *(const v8bf*)((const char*)As + abase[mi] + ((ks * 64 + ln4 * 16) ^ axor[mi])); } \
    _Pragma("unroll") \
    for (int ni = 0; ni < 2; ++ni) { _Pragma("unroll") \
        for (int ks = 0; ks < 2; ++ks) { \
            int in0 = ks * 128 + ln4 * 32; \
            f32x4 lo1 = *(const f32x4*)((const char*)B1s + bbase[ni] + ((in0) ^ bxor[ni])); \
            f32x4 hi1 = *(const f32x4*)((const char*)B1s + bbase[ni] + ((in0 + 16) ^ bxor[ni])); \
            f32x4 lo3 = *(const f32x4*)((const char*)B3s + bbase[ni] + ((in0) ^ bxor[ni])); \
            f32x4 hi3 = *(const f32x4*)((const char*)B3s + bbase[ni] + ((in0 + 16) ^ bxor[ni])); \
            b1f[ni][ks] = pack8(lo1, hi1); \
            b3f[ni][ks] = pack8(lo3, hi3); } } \
    _Pragma("unroll") \
    for (int mi = 0; mi < 4; ++mi) { _Pragma("unroll") \
        for (int ni = 0; ni < 2; ++ni) { _Pragma("unroll") \
            for (int ks = 0; ks < 2; ++ks) { \
                acc1[mi][ni] = __builtin_amdgcn_mfma_f32_16x16x32_bf16(af[mi][ks], b1f[ni][ks], acc1[mi][ni], 0, 0, 0); \
                acc3[mi][ni] = __builtin_amdgcn_mfma_f32_16x16x32_bf16(af[mi][ks], b3f[ni][ks], acc3[mi][ni], 0, 0, 0); } } } \
    } while (0)

    DMA_ALL1(0);
    for (int ks = 0; ks < HDIM / 64; ++ks) {
        WAITVM0();
        BARRIER();
        CMP1();
        WAITLGKM0();
        BARRIER();
        if (ks + 1 < HDIM / 64) DMA_ALL1(ks + 1);
    }
#undef DMA_ALL1
#undef CMP1

    const int rj = ln4 * 4;
#pragma unroll
    for (int mi = 0; mi < 4; ++mi) {
#pragma unroll
        for (int j = 0; j < 4; ++j) {
            int rm = wm + mi * 16 + rj + j;
            if (rm < rows) {
                size_t rowoff = (size_t)(slot0 + rm) * FDIM + n0 + wn;
#pragma unroll
                for (int ni = 0; ni < 2; ++ni) {
                    float h1 = acc1[mi][ni][j];
                    float h3 = acc3[mi][ni][j];
                    float sv = (h1 / (1.f + __expf(-h1))) * h3;
                    act[rowoff + ni * 16 + lr] = (__bf16)sv;
                }
            }
        }
    }
}

// ---------------- GEMM2: y_part = act @ w2^T; BM=64 BN=64 BK=64, split-K x2, single-buf ----------------
__global__ __launch_bounds__(256, 2) void moe_gemm2(
    const __bf16* __restrict__ act, const float* __restrict__ w2g,
    const int* __restrict__ counts, const int* __restrict__ offsets,
    const int* __restrict__ t2e, const int* __restrict__ t2m,
    const int* __restrict__ nt2,
    float* __restrict__ y0, float* __restrict__ y1)
{
    const int ty = blockIdx.y;
    if (ty >= *nt2) return;
    const int e = t2e[ty];
    const int m0 = t2m[ty];
    const int Me = counts[e];
    const int rows = min(64, Me - m0);
    const int slot0 = offsets[e] + m0;
    const int n0 = blockIdx.x * 64;
    const int kz = blockIdx.z;
    float* yout = kz ? y1 : y0;
    const size_t kbase = (size_t)kz * KPER2;

    __shared__ __align__(16) __bf16 As[64 * 64];    // 8 KB
    __shared__ __align__(16) float  Bs[64 * 64];    // 16 KB

    const int tid = threadIdx.x;
    const int lane = tid & 63;
    const int wv = tid >> 6;
    const int ln4 = lane >> 4;
    const int lr = lane & 15;
    const int wm = (wv >> 1) * 32;
    const int wn = (wv & 1) * 32;

    f32x4 acc[2][2];
#pragma unroll
    for (int i = 0; i < 2; ++i)
#pragma unroll
        for (int j = 0; j < 2; ++j) acc[i][j] = (f32x4){0.f, 0.f, 0.f, 0.f};

    // A: 512 chunks (64 rows x 8); 2 per thread
    const char* asrc[2];
#pragma unroll
    for (int i = 0; i < 2; ++i) {
        int c = i * 256 + tid;
        int r = c >> 3;
        int rr = (r < rows) ? r : 0;
        int sj = (c & 7) ^ (r & 7);
        asrc[i] = (const char*)(act + (size_t)(slot0 + rr) * FDIM + kbase) + sj * 16;
    }
    // B: 1024 chunks (64 rows x 16); 4 per thread
    const char* bsrc[4];
#pragma unroll
    for (int i = 0; i < 4; ++i) {
        int c = i * 256 + tid;
        int r = c >> 4;
        int sj = (c & 15) ^ (r & 15);
        bsrc[i] = (const char*)(w2g + ((size_t)e * HDIM + n0 + r) * FDIM + kbase) + sj * 16;
    }

#define DMA_ALL2(K0) do { \
    _Pragma("unroll") \
    for (int i = 0; i < 2; ++i) \
        DMA16(asrc[i] + (size_t)(K0) * 128, (char*)As + (i * 256 + wv * 64) * 16); \
    _Pragma("unroll") \
    for (int i = 0; i < 4; ++i) \
        DMA16(bsrc[i] + (size_t)(K0) * 256, (char*)Bs + (i * 256 + wv * 64) * 16); \
    } while (0)

    int abase[2], axor[2];
#pragma unroll
    for (int i = 0; i < 2; ++i) {
        int row = wm + i * 16 + lr;
        abase[i] = row * 128;
        axor[i] = (row & 7) << 4;
    }
    int bbase[2], bxor[2];
#pragma unroll
    for (int i = 0; i < 2; ++i) {
        int row = wn + i * 16 + lr;
        bbase[i] = row * 256;
        bxor[i] = (row & 15) << 4;
    }

#define CMP2() do { \
    v8bf af[2][2], bf[2][2]; \
    _Pragma("unroll") \
    for (int mi = 0; mi < 2; ++mi) { _Pragma("unroll") \
        for (int ks = 0; ks < 2; ++ks) \
            af[mi][ks] = *(const v8bf*)((const char*)As + abase[mi] + ((ks * 64 + ln4 * 16) ^ axor[mi])); } \
    _Pragma("unroll") \
    for (int ni = 0; ni < 2; ++ni) { _Pragma("unroll") \
        for (int ks = 0; ks < 2; ++ks) { \
            int in0 = ks * 128 + ln4 * 32; \
            f32x4 lo = *(const f32x4*)((const char*)Bs + bbase[ni] + ((in0) ^ bxor[ni])); \
            f32x4 hi = *(const f32x4*)((const char*)Bs + bbase[ni] + ((in0 + 16) ^ bxor[ni])); \
            bf[ni][ks] = pack8(lo, hi); } } \
    _Pragma("unroll") \
    for (int mi = 0; mi < 2; ++mi) { _Pragma("unroll") \
        for (int ni = 0; ni < 2; ++ni) { _Pragma("unroll") \
            for (int ks = 0; ks < 2; ++ks) \
                acc[mi][ni] = __builtin_amdgcn_mfma_f32_16x16x32_bf16(af[mi][ks], bf[ni][ks], acc[mi][ni], 0, 0, 0); } } \
    } while (0)

    DMA_ALL2(0);
    for (int ks = 0; ks < KPER2 / 64; ++ks) {
        WAITVM0();
        BARRIER();
        CMP2();
        WAITLGKM0();
        BARRIER();
        if (ks + 1 < KPER2 / 64) DMA_ALL2(ks + 1);
    }
#undef DMA_ALL2
#undef CMP2

    const int rj = ln4 * 4;
#pragma unroll
    for (int mi = 0; mi < 2; ++mi) {
#pragma unroll
        for (int j = 0; j < 4; ++j) {
            int rm = wm + mi * 16 + rj + j;
            if (rm < rows) {
                size_t rowoff = (size_t)(slot0 + rm) * HDIM + n0 + wn;
#pragma unroll
                for (int ni = 0; ni < 2; ++ni)
                    yout[rowoff + ni * 16 + lr] = acc[mi][ni][j];
            }
        }
    }
}

// ---------------- combine: out[t] = w0*(y0+y1)[s0] + w1*(y0+y1)[s1] ----------------
__global__ __launch_bounds__(256) void moe_combine(
    const float* __restrict__ y0, const float* __restrict__ y1,
    const int* __restrict__ slot_of, const float* __restrict__ pair_wt,
    float* __restrict__ out)
{
    const int t = blockIdx.x;
    const int tid = threadIdx.x;
    const int s0 = slot_of[2 * t];
    const int s1 = slot_of[2 * t + 1];
    const float w0 = pair_wt[s0];
    const float w1 = pair_wt[s1];
    const float4 a0 = *(const float4*)(y0 + (size_t)s0 * HDIM + tid * 4);
    const float4 a1 = *(const float4*)(y1 + (size_t)s0 * HDIM + tid * 4);
    const float4 b0 = *(const float4*)(y0 + (size_t)s1 * HDIM + tid * 4);
    const float4 b1 = *(const float4*)(y1 + (size_t)s1 * HDIM + tid * 4);
    float4 o;
    o.x = w0 * (a0.x + a1.x) + w1 * (b0.x + b1.x);
    o.y = w0 * (a0.y + a1.y) + w1 * (b0.y + b1.y);
    o.z = w0 * (a0.z + a1.z) + w1 * (b0.z + b1.z);
    o.w = w0 * (a0.w + a1.w) + w1 * (b0.w + b1.w);
    *(float4*)(out + (size_t)t * HDIM + tid * 4) = o;
}

extern "C" void kernel_launch(void* const* d_in, const int* in_sizes, int n_in,
                              void* d_out, int out_size, void* d_ws, size_t ws_size,
                              hipStream_t stream) {
    const float* x   = (const float*)d_in[0];
    const float* gw  = (const float*)d_in[1];
    const float* w1  = (const float*)d_in[2];
    const float* w2  = (const float*)d_in[3];
    const float* w3  = (const float*)d_in[4];

    float* out    = (float*)d_out;
    float* logits = out + (size_t)NTOK * HDIM;

    char* ws = (char*)d_ws;
    int*    counts     = (int*)(ws + OFF_COUNTS);
    int*    offsets    = (int*)(ws + OFF_OFFSETS);
    int*    nt1        = (int*)(ws + OFF_NT1);
    int*    nt2        = (int*)(ws + OFF_NT2);
    int*    t1e        = (int*)(ws + OFF_T1E);
    int*    t1m        = (int*)(ws + OFF_T1M);
    int*    t2e        = (int*)(ws + OFF_T2E);
    int*    t2m        = (int*)(ws + OFF_T2M);
    int*    tok_idx    = (int*)(ws + OFF_TOKIDX);
    float*  tok_wt     = (float*)(ws + OFF_TOKWT);
    int*    pair_token = (int*)(ws + OFF_PAIRTOK);
    float*  pair_wt    = (float*)(ws + OFF_PAIRWT);
    int*    slot_of    = (int*)(ws + OFF_SLOTOF);
    __bf16* xb         = (__bf16*)(ws + OFF_XB);
    __bf16* act        = (__bf16*)(ws + OFF_ACT);
    float*  yb0        = (float*)(ws + OFF_Y0);
    float*  yb1        = (float*)(ws + OFF_Y1);

    hipMemsetAsync(counts, 0, 64, stream);

    moe_cvtx<<<dim3(NTOK * HDIM / 1024), dim3(256), 0, stream>>>(x, xb);
    moe_router<<<dim3(NTOK / 4), dim3(256), 0, stream>>>(x, gw, logits, counts, tok_idx, tok_wt);
    moe_scatter<<<dim3(1), dim3(256), 0, stream>>>(counts, tok_idx, tok_wt, offsets,
                                                   pair_token, pair_wt, slot_of,
                                                   t1e, t1m, nt1, t2e, t2m, nt2);
    moe_gemm1<<<dim3(FDIM / 64, MAXT1), dim3(256), 0, stream>>>(
        xb, w1, w3, counts, offsets, pair_token, t1e, t1m, nt1, act);
    moe_gemm2<<<dim3(HDIM / 64, MAXT2, KSPLIT2), dim3(256), 0, stream>>>(
        act, w2, counts, offsets, t2e, t2m, nt2, yb0, yb1);
    moe_combine<<<dim3(NTOK), dim3(256), 0, stream>>>(yb0, yb1, slot_of, pair_wt, out);
}